// Round 10
// baseline (96.221 us; speedup 1.0000x reference)
//
#include <hip/hip_runtime.h>

// Problem constants
#define B_   4
#define C_   64
#define H_   192
#define W_   640
#define D_   96     // disparities
#define TWB  64     // w1 columns per block
#define NDL  7      // 16-wide delta tiles covering d in [0,96)
#define HW_  (H_ * W_)
#define GP   97     // Gs pitch: [w_local][d], odd -> bank = (w+d)%32, <=2-way
#define NWG  7680   // (W/TWB) * B * H = 8 * 960

typedef __attribute__((ext_vector_type(8))) short short8;
typedef __attribute__((ext_vector_type(4))) float float4v;

// bank swizzle: spreads row bits into the 8x16B slot index of a 128B row
#define SWZ(x) ((((x) ^ ((x) >> 3)) & 7) << 3)

// packed f32x2 -> bf16x2 (single HW instruction, RTNE).
// volatile: must not be hoisted above the s_waitcnt that lands its inputs.
__device__ inline unsigned int pk2(float lo, float hi) {
    unsigned int r;
    asm volatile("v_cvt_pk_bf16_f32 %0, %1, %2" : "=v"(r) : "v"(lo), "v"(hi));
    return r;
}

// forced async 16B load: compiler can't serialize or auto-wait these
#define GLOAD(dst, addr) \
    asm volatile("global_load_dwordx4 %0, %1, off" : "=v"(dst) : "v"(addr))

// out[b,0,d,h,w] = sum_c L[b,c,h,w] * R[b,c,h,(w - d*s) mod W] = G[w][w - s*d]
__global__ __launch_bounds__(256)
void cost_volume_mfma(const float* __restrict__ Lp,
                      const float* __restrict__ Rp,
                      const int* __restrict__ dirp,
                      float* __restrict__ out)
{
    const int s = dirp[0];   // +1 or -1, uniform across grid

    // 28672 B union:
    //   staging: Lb [64][64] u16 @ byte 0, Rb [160][64] u16 @ byte 8192
    //   then reused as Gs [64 w][GP=97 d] f32 (24832 B)
    __shared__ unsigned int smem[7168];
    unsigned int* Lw = smem;
    unsigned int* Rw = smem + 2048;                 // byte 8192
    const unsigned short* Lb = (const unsigned short*)smem;         // byte 0
    const unsigned short* Rb = (const unsigned short*)smem + 4096;  // byte 8192
    float* Gs = (float*)smem;

    // XCD-chunked bijective swizzle: NWG = 7680 = 8 * 960
    const int orig = blockIdx.x;
    const int nid  = (orig & 7) * (NWG / 8) + (orig >> 3);
    const int bh   = nid / 10;
    const int slab = nid - bh * 10;
    const int b  = bh / H_;
    const int h  = bh - b * H_;
    const int w0 = slab * TWB;
    const int rbase = (s == 1) ? (w0 - 96) : w0;    // global col of Rb k=0
    const int rbias = (s == 1) ? 96 : 0;            // B-frag tile bias

    const int tid = threadIdx.x;
    const float* Lrow = Lp + ((size_t)b * C_ * H_ + h) * W_;
    const float* Rrow = Rp + ((size_t)b * C_ * H_ + h) * W_;

    const int w4 = tid & 15;          // L-stage + epilogue w group
    const int cL = (tid >> 4) * 2;    // L channel pair (0..30)
    const int k8 = tid & 7;           // R k4 low bits
    const int cR = (tid >> 3) * 2;    // R channel pair (0..62)

    // ---- issue ALL 14 staging loads asynchronously (forced MLP) ----
    float4v pf0, pf1, pf2, pf3, pf4, pf5, pf6, pf7, pf8, pf9, pf10, pf11, pf12, pf13;
    {
        const float* p0 = Lrow + (size_t)cL * HW_ + w0 + 4 * w4;
        GLOAD(pf0, p0);
        GLOAD(pf1, p0 + HW_);
        GLOAD(pf2, p0 + (size_t)32 * HW_);
        GLOAD(pf3, p0 + (size_t)33 * HW_);
    }
    {
        const float* pc = Rrow + (size_t)cR * HW_;
        int col0 = rbase + 4 * k8;
        if (col0 < 0)   col0 += W_;
        if (col0 >= W_) col0 -= W_;
        int col1 = rbase + 4 * (k8 + 8);
        if (col1 < 0)   col1 += W_;
        if (col1 >= W_) col1 -= W_;
        int col2 = rbase + 4 * (k8 + 16);
        if (col2 < 0)   col2 += W_;
        if (col2 >= W_) col2 -= W_;
        int col3 = rbase + 4 * (k8 + 24);
        if (col3 < 0)   col3 += W_;
        if (col3 >= W_) col3 -= W_;
        int col4 = rbase + 4 * (k8 + 32);
        if (col4 < 0)   col4 += W_;
        if (col4 >= W_) col4 -= W_;
        GLOAD(pf4,  pc + col0);
        GLOAD(pf5,  pc + HW_ + col0);
        GLOAD(pf6,  pc + col1);
        GLOAD(pf7,  pc + HW_ + col1);
        GLOAD(pf8,  pc + col2);
        GLOAD(pf9,  pc + HW_ + col2);
        GLOAD(pf10, pc + col3);
        GLOAD(pf11, pc + HW_ + col3);
        GLOAD(pf12, pc + col4);
        GLOAD(pf13, pc + HW_ + col4);
    }

    // ---- L landed (oldest 4): convert while R still in flight ----
    asm volatile("s_waitcnt vmcnt(10)" ::: "memory");
    __builtin_amdgcn_sched_barrier(0);   // rule #18: block reg-op hoisting past waitcnt
#pragma unroll
    for (int u0 = 0; u0 < 2; ++u0) {
        const int c = cL + 32 * u0;
        const float4v a = u0 ? pf2 : pf0;
        const float4v q = u0 ? pf3 : pf1;
#pragma unroll
        for (int j = 0; j < 4; ++j) {
            const int w = 4 * w4 + j;
            Lw[w * 32 + ((c ^ SWZ(w)) >> 1)] = pk2(a[j], q[j]);
        }
    }

    // ---- R landed: convert + stage ----
    asm volatile("s_waitcnt vmcnt(0)" ::: "memory");
    __builtin_amdgcn_sched_barrier(0);
#pragma unroll
    for (int u0 = 0; u0 < 5; ++u0) {
        const float4v a = (u0 == 0) ? pf4  : (u0 == 1) ? pf6  : (u0 == 2) ? pf8  : (u0 == 3) ? pf10 : pf12;
        const float4v q = (u0 == 0) ? pf5  : (u0 == 1) ? pf7  : (u0 == 2) ? pf9  : (u0 == 3) ? pf11 : pf13;
#pragma unroll
        for (int j = 0; j < 4; ++j) {
            const int k = 4 * (k8 + 8 * u0) + j;
            Rw[k * 32 + ((cR ^ SWZ(k)) >> 1)] = pk2(a[j], q[j]);
        }
    }
    __syncthreads();   // staging visible

    // ---- MFMA: wave wv owns w1 tile [w0+16wv, +16), 7 delta tiles x K=64 ----
    const int lane = tid & 63;
    const int wv   = tid >> 6;
    const int n15  = lane & 15;
    const int lg   = lane >> 4;

    short8 afrag[2];
    {
        const int w = 16 * wv + n15;
#pragma unroll
        for (int q = 0; q < 2; ++q) {
            const int c = lg * 8 + 32 * q;
            afrag[q] = *(const short8*)&Lb[w * 64 + (c ^ SWZ(w))];
        }
    }

    float4v acc[NDL];
#pragma unroll
    for (int dl = 0; dl < NDL; ++dl) acc[dl] = (float4v)0.f;

#pragma unroll
    for (int dl = 0; dl < NDL; ++dl) {
        const int k = rbias + 16 * wv - s * 16 * dl + n15;   // 0..159
#pragma unroll
        for (int q = 0; q < 2; ++q) {
            const int c = lg * 8 + 32 * q;
            const short8 bfrag = *(const short8*)&Rb[k * 64 + (c ^ SWZ(k))];
            acc[dl] = __builtin_amdgcn_mfma_f32_16x16x32_bf16(afrag[q], bfrag, acc[dl], 0, 0, 0);
        }
    }
    __syncthreads();   // staging reads done; safe to overwrite with Gs

    // ---- scatter into Gs[w_local][d] (pitch 97, odd -> conflict-free) ----
    // D layout (16x16x32): n = lane&15 (w2), m = (lane>>4)*4 + reg (w1)
#pragma unroll
    for (int dl = 0; dl < NDL; ++dl) {
#pragma unroll
        for (int r = 0; r < 4; ++r) {
            const int m = lg * 4 + r;
            const int d = 16 * dl + s * (m - n15);
            if (0 <= d && d < D_)
                Gs[(16 * wv + m) * GP + d] = acc[dl][r];
        }
    }
    __syncthreads();   // Gs complete

    // ---- epilogue: scalar LDS reads (bank-clean), float4 global stores ----
    const int dg = tid >> 4;
#pragma unroll
    for (int p = 0; p < 6; ++p) {
        const int d = dg + 16 * p;
        float4v v;
        v[0] = Gs[(4 * w4 + 0) * GP + d];
        v[1] = Gs[(4 * w4 + 1) * GP + d];
        v[2] = Gs[(4 * w4 + 2) * GP + d];
        v[3] = Gs[(4 * w4 + 3) * GP + d];
        *(float4v*)(out + ((size_t)(b * D_ + d) * H_ + h) * W_ + w0 + 4 * w4) = v;
    }
}

extern "C" void kernel_launch(void* const* d_in, const int* in_sizes, int n_in,
                              void* d_out, int out_size, void* d_ws, size_t ws_size,
                              hipStream_t stream)
{
    const float* un_l = (const float*)d_in[0];
    const float* un_r = (const float*)d_in[1];
    const int*   dirp = (const int*)d_in[2];
    float* out = (float*)d_out;

    dim3 grid(NWG);    // 7680
    dim3 block(256);

    // single kernel, runtime-uniform direction
    cost_volume_mfma<<<grid, block, 0, stream>>>(un_l, un_r, dirp, out);
}